// Round 4
// baseline (1332.208 us; speedup 1.0000x reference)
//
#include <hip/hip_runtime.h>

#define NB 4
#define NP 8192
#define NS 1024
#define NK 32
#define CNT_ALL 131072.0f   // NB*NS*NK

typedef float v2f __attribute__((ext_vector_type(2)));

__device__ __forceinline__ v2f pk_add(v2f a, v2f b)
{
    v2f d;
    asm("v_pk_add_f32 %0, %1, %2" : "=v"(d) : "v"(a), "v"(b));
    return d;
}
__device__ __forceinline__ v2f pk_mul(v2f a, v2f b)
{
    v2f d;
    asm("v_pk_mul_f32 %0, %1, %2" : "=v"(d) : "v"(a), "v"(b));
    return d;
}

template <int CTRL>
__device__ __forceinline__ unsigned dpp_max_u32(unsigned m)
{
    unsigned o = (unsigned)__builtin_amdgcn_update_dpp((int)m, (int)m, CTRL, 0xF, 0xF, false);
    return (o > m) ? o : m;
}

// ---------------------------------------------------------------- FPS
// One block (512 thr, 8 waves) per batch. 16 pts/thread BLOCKED so lane order ==
// index order (numpy first-max tie-break). Distance math forced to v_pk_*_f32
// via inline asm (6 instr / 2 pts); min+argmax tracking scalar. Wave argmax:
// u32 DPP max on float bits (dist>=0) + ballot/ffs/readlane. Cross-wave: u64
// {val,idx} in LDS, u32 DPP max on val + ballot/readlane (lowest wave wins ties
// == lowest index). xyz staged in LDS SoA (coalesced, conflict-free writes).
__global__ __launch_bounds__(512, 2) void fps_kernel(const float* __restrict__ xyz,
                                                     float* __restrict__ newxyz)
{
#pragma clang fp contract(off)
    const int b = blockIdx.x;
    const int tid = threadIdx.x;
    const int lane = tid & 63;
    const int w = tid >> 6;                 // 8 waves
    const float* xb = xyz + (size_t)b * NP * 3;

    __shared__ float s_px[NP], s_py[NP], s_pz[NP];      // 96 KB
    __shared__ unsigned long long s_kv[2][8];

    // coalesced global -> LDS staging (lane reads 12B stride; LDS writes stride-1)
#pragma unroll
    for (int k = 0; k < 16; ++k) {
        const int i = k * 512 + tid;
        s_px[i] = xb[3 * i + 0];
        s_py[i] = xb[3 * i + 1];
        s_pz[i] = xb[3 * i + 2];
    }
    __syncthreads();

    v2f px[8], py[8], pz[8], dist[8];
    const int base = tid << 4;
#pragma unroll
    for (int m = 0; m < 8; ++m) {
        const int p0 = base + 2 * m;
        px[m] = v2f{s_px[p0], s_px[p0 + 1]};
        py[m] = v2f{s_py[p0], s_py[p0 + 1]};
        pz[m] = v2f{s_pz[p0], s_pz[p0 + 1]};
        dist[m] = v2f{1e10f, 1e10f};
    }
    float cx = s_px[0], cy = s_py[0], cz = s_pz[0];
    float* ob = newxyz + (size_t)b * NS * 3;

    for (int it = 0; it < NS; ++it) {
        if (tid == 0) { ob[it * 3 + 0] = cx; ob[it * 3 + 1] = cy; ob[it * 3 + 2] = cz; }
        const v2f ncx = v2f{-cx, -cx}, ncy = v2f{-cy, -cy}, ncz = v2f{-cz, -cz};
        float bd0 = -1.0f, bd1 = -1.0f;
        int bj0 = 0, bj1 = 0;
#pragma unroll
        for (int m = 0; m < 8; ++m) {
            v2f dx = pk_add(px[m], ncx);            // px - cx (exact)
            v2f dy = pk_add(py[m], ncy);
            v2f dz = pk_add(pz[m], ncz);
            v2f xx = pk_mul(dx, dx);
            v2f yy = pk_mul(dy, dy);
            v2f zz = pk_mul(dz, dz);
            v2f d = pk_add(pk_add(xx, yy), zz);     // (dx2+dy2)+dz2, numpy order
            float d0 = fminf(dist[m].x, d.x);
            float d1 = fminf(dist[m].y, d.y);
            dist[m].x = d0;
            dist[m].y = d1;
            bool t0 = d0 > bd0;                      // strict >: first max wins
            bd0 = t0 ? d0 : bd0;
            bj0 = t0 ? 2 * m : bj0;
            bool t1 = d1 > bd1;
            bd1 = t1 ? d1 : bd1;
            bj1 = t1 ? 2 * m + 1 : bj1;
        }
        // merge even/odd chains; tie -> smaller local index
        const bool tm = (bd1 > bd0) || ((bd1 == bd0) && (bj1 < bj0));
        const float bd = tm ? bd1 : bd0;
        const int ibest = base + (tm ? bj1 : bj0);
        // wave max of dist bits (bd >= 0 so float bits order-preserving as u32)
        const unsigned ub = __float_as_uint(bd);
        unsigned m0 = dpp_max_u32<0xB1>(ub);    // quad_perm xor1
        m0 = dpp_max_u32<0x4E>(m0);             // quad_perm xor2
        m0 = dpp_max_u32<0x141>(m0);            // row_half_mirror
        m0 = dpp_max_u32<0x140>(m0);            // row_mirror
        m0 = dpp_max_u32<0x142>(m0);            // row_bcast15
        m0 = dpp_max_u32<0x143>(m0);            // row_bcast31 -> lane63 = wave max
        const unsigned maxbits = (unsigned)__builtin_amdgcn_readlane((int)m0, 63);
        const unsigned long long bm = __ballot(ub == maxbits);
        const int srclane = __ffsll(bm) - 1;    // lowest lane = lowest idx
        const int wbi = __builtin_amdgcn_readlane(ibest, srclane);
        if (lane == 0)
            s_kv[it & 1][w] = ((unsigned long long)maxbits << 32) | (unsigned)wbi;
        __syncthreads();
        const unsigned long long kv = s_kv[it & 1][lane & 7];
        const unsigned vv = (unsigned)(kv >> 32);
        const unsigned ii = (unsigned)kv;
        unsigned g0 = dpp_max_u32<0xB1>(vv);
        g0 = dpp_max_u32<0x4E>(g0);
        g0 = dpp_max_u32<0x141>(g0);            // every lane: max over the 8 wave keys
        const unsigned long long mm = __ballot(vv == g0);
        const int l0 = __ffsll(mm) - 1;         // lowest matching lane = lowest wave = lowest idx
        const int fi = __builtin_amdgcn_readlane((int)ii, l0);
        cx = s_px[fi]; cy = s_py[fi]; cz = s_pz[fi];   // LDS broadcast
    }
}

// ---------------------------------------------------------------- ball query
// one wave per centroid; collect first NK point-indices (ascending) with d^2 <= r^2
__global__ __launch_bounds__(256) void ballq_kernel(const float* __restrict__ xyz,
                                                    const float* __restrict__ newxyz,
                                                    int* __restrict__ idxb)
{
#pragma clang fp contract(off)
    __shared__ int s_ball[4][NK];
    const int w = threadIdx.x >> 6;
    const int lane = threadIdx.x & 63;
    const int sg = blockIdx.x * 4 + w;          // 0..4095
    const int b = sg >> 10;
    const float rr = (float)(0.2 * 0.2);        // == f32(0.04000000000000001)
    const float cx = newxyz[sg * 3 + 0];
    const float cy = newxyz[sg * 3 + 1];
    const float cz = newxyz[sg * 3 + 2];
    const float* xb = xyz + (size_t)b * NP * 3;
    int cnt = 0;
    for (int base = 0; base < NP && cnt < NK; base += 64) {
        const int p = base + lane;
        float dx = xb[p * 3 + 0] - cx;
        float dy = xb[p * 3 + 1] - cy;
        float dz = xb[p * 3 + 2] - cz;
        float d = (dx * dx + dy * dy) + dz * dz;
        bool in = (d <= rr);
        unsigned long long mask = __ballot(in);
        int before = __popcll(mask & ((1ull << lane) - 1ull));
        int pos = cnt + before;
        if (in && pos < NK) s_ball[w][pos] = p;
        cnt += (int)__popcll(mask);
    }
    cnt = min(cnt, NK);
    if (lane < NK) {
        int v = (lane < cnt) ? s_ball[w][lane] : s_ball[w][0];
        idxb[(size_t)sg * NK + lane] = v;
    }
}

// ---------------------------------------------------------------- layer 1 (19 -> 64), pre-BN output
__global__ __launch_bounds__(256) void linear1_kernel(const float* __restrict__ xyz,
                                                      const float* __restrict__ pts,
                                                      const float* __restrict__ newxyz,
                                                      const int* __restrict__ idxb,
                                                      const float* __restrict__ w1,
                                                      const float* __restrict__ b1,
                                                      float* __restrict__ y1)
{
    const int P = blockIdx.x * 256 + threadIdx.x;    // 0..131071
    const int b = P >> 15;
    const int s = (P >> 5) & (NS - 1);
    const int id = idxb[P];
    const float* pp = xyz + ((size_t)b * NP + id) * 3;
    const float* cp = newxyz + ((size_t)b * NS + s) * 3;
    float f[19];
    f[0] = pp[0] - cp[0];
    f[1] = pp[1] - cp[1];
    f[2] = pp[2] - cp[2];
    const float* q = pts + ((size_t)b * NP + id) * 16;
#pragma unroll
    for (int j = 0; j < 16; ++j) f[3 + j] = q[j];
    float y[64];
#pragma unroll 4
    for (int c = 0; c < 64; ++c) {
        float a = b1[c];
#pragma unroll
        for (int j = 0; j < 19; ++j) a += w1[c * 19 + j] * f[j];
        y[c] = a;
    }
    float4* o = (float4*)(y1 + (size_t)P * 64);
#pragma unroll
    for (int t = 0; t < 16; ++t) o[t] = make_float4(y[4*t], y[4*t+1], y[4*t+2], y[4*t+3]);
}

// ---------------------------------------------------------------- per-channel sum/sumsq reduction
template <int C>
__global__ __launch_bounds__(256) void stats_kernel(const float* __restrict__ y,
                                                    float* __restrict__ sums,
                                                    float* __restrict__ sqs)
{
    const int RPB = 256 / C;
    const int c = threadIdx.x & (C - 1);
    const int rq = threadIdx.x / C;
    float s = 0.f, q = 0.f;
    for (int r = blockIdx.x * RPB + rq; r < 131072; r += gridDim.x * RPB) {
        float v = y[(size_t)r * C + c];
        s += v; q += v * v;
    }
    __shared__ float ls[256], lq[256];
    ls[threadIdx.x] = s; lq[threadIdx.x] = q;
    __syncthreads();
    if (threadIdx.x < C) {
        for (int i = 1; i < RPB; ++i) { s += ls[i * C + threadIdx.x]; q += lq[i * C + threadIdx.x]; }
        atomicAdd(&sums[(blockIdx.x & 7) * C + threadIdx.x], s);
        atomicAdd(&sqs [(blockIdx.x & 7) * C + threadIdx.x], q);
    }
}

template <int C>
__global__ void finalize_kernel(const float* __restrict__ sums, const float* __restrict__ sqs,
                                const float* __restrict__ g, const float* __restrict__ be,
                                float* __restrict__ scale, float* __restrict__ shift)
{
    const int c = threadIdx.x;
    if (c >= C) return;
    float s = 0.f, q = 0.f;
    for (int sh = 0; sh < 8; ++sh) { s += sums[sh * C + c]; q += sqs[sh * C + c]; }
    float mean = s / CNT_ALL;
    float var = q / CNT_ALL - mean * mean;
    float sc = g[c] / sqrtf(var + 1e-5f);
    scale[c] = sc;
    shift[c] = be[c] - mean * sc;
}

// ---------------------------------------------------------------- layer 2 (64 -> 64), pre-BN output
__global__ __launch_bounds__(256) void linear2_kernel(const float* __restrict__ y1,
                                                      const float* __restrict__ sc1,
                                                      const float* __restrict__ sh1,
                                                      const float* __restrict__ w2,
                                                      const float* __restrict__ b2,
                                                      float* __restrict__ y2)
{
    const int P = blockIdx.x * 256 + threadIdx.x;
    const float4* yi = (const float4*)(y1 + (size_t)P * 64);
    float x[64];
#pragma unroll
    for (int t = 0; t < 16; ++t) {
        float4 v = yi[t];
        x[4*t+0] = fmaxf(v.x * sc1[4*t+0] + sh1[4*t+0], 0.f);
        x[4*t+1] = fmaxf(v.y * sc1[4*t+1] + sh1[4*t+1], 0.f);
        x[4*t+2] = fmaxf(v.z * sc1[4*t+2] + sh1[4*t+2], 0.f);
        x[4*t+3] = fmaxf(v.w * sc1[4*t+3] + sh1[4*t+3], 0.f);
    }
    float y[64];
#pragma unroll 4
    for (int c = 0; c < 64; ++c) {
        float a = b2[c];
#pragma unroll
        for (int j = 0; j < 64; ++j) a += w2[c * 64 + j] * x[j];
        y[c] = a;
    }
    float4* o = (float4*)(y2 + (size_t)P * 64);
#pragma unroll
    for (int t = 0; t < 16; ++t) o[t] = make_float4(y[4*t], y[4*t+1], y[4*t+2], y[4*t+3]);
}

// ---------------------------------------------------------------- layer 3 stats (bn2+relu inline, LDS-staged group)
__global__ __launch_bounds__(128) void l3stats_kernel(const float* __restrict__ y2,
                                                      const float* __restrict__ sc2,
                                                      const float* __restrict__ sh2,
                                                      const float* __restrict__ w3,
                                                      const float* __restrict__ b3,
                                                      float* __restrict__ sums,
                                                      float* __restrict__ sqs)
{
    __shared__ float s_x[NK * 64];           // 8 KB: bn2+relu'd group
    const int g = blockIdx.x;                // 4096 groups
    const int c = threadIdx.x;               // 128 out channels
    // stage: 2048 elts, float4 per thread x4, channel base (4c)&63 i-invariant
    {
        const float4* yg = (const float4*)(y2 + (size_t)g * NK * 64);
        const int ch = (4 * c) & 63;
        const float s0 = sc2[ch], s1 = sc2[ch + 1], s2 = sc2[ch + 2], s3 = sc2[ch + 3];
        const float h0 = sh2[ch], h1 = sh2[ch + 1], h2 = sh2[ch + 2], h3 = sh2[ch + 3];
        float4* sx4 = (float4*)s_x;
#pragma unroll
        for (int i = 0; i < 4; ++i) {
            float4 v = yg[i * 128 + c];
            float4 o;
            o.x = fmaxf(v.x * s0 + h0, 0.f);
            o.y = fmaxf(v.y * s1 + h1, 0.f);
            o.z = fmaxf(v.z * s2 + h2, 0.f);
            o.w = fmaxf(v.w * s3 + h3, 0.f);
            sx4[i * 128 + c] = o;
        }
    }
    __syncthreads();
    float w[64];
    const float4* wr = (const float4*)(w3 + (size_t)c * 64);
#pragma unroll
    for (int t = 0; t < 16; ++t) {
        float4 v = wr[t];
        w[4*t+0] = v.x; w[4*t+1] = v.y; w[4*t+2] = v.z; w[4*t+3] = v.w;
    }
    const float bs = b3[c];
    float s = 0.f, q = 0.f;
#pragma unroll 2
    for (int k = 0; k < NK; ++k) {
        const float4* xk = (const float4*)(s_x + k * 64);
        float a = bs;
#pragma unroll
        for (int t = 0; t < 16; ++t) {
            float4 v = xk[t];               // broadcast LDS read
            a += w[4*t+0] * v.x + w[4*t+1] * v.y + w[4*t+2] * v.z + w[4*t+3] * v.w;
        }
        s += a; q += a * a;
    }
    atomicAdd(&sums[(g & 7) * 128 + c], s);
    atomicAdd(&sqs [(g & 7) * 128 + c], q);
}

// ---------------------------------------------------------------- layer 3 recompute + bn3 + relu + maxpool
__global__ __launch_bounds__(128) void final_kernel(const float* __restrict__ y2,
                                                    const float* __restrict__ sc2,
                                                    const float* __restrict__ sh2,
                                                    const float* __restrict__ w3,
                                                    const float* __restrict__ b3,
                                                    const float* __restrict__ sc3,
                                                    const float* __restrict__ sh3,
                                                    float* __restrict__ out_np)
{
    __shared__ float s_x[NK * 64];
    const int g = blockIdx.x;
    const int c = threadIdx.x;
    {
        const float4* yg = (const float4*)(y2 + (size_t)g * NK * 64);
        const int ch = (4 * c) & 63;
        const float s0 = sc2[ch], s1 = sc2[ch + 1], s2 = sc2[ch + 2], s3 = sc2[ch + 3];
        const float h0 = sh2[ch], h1 = sh2[ch + 1], h2 = sh2[ch + 2], h3 = sh2[ch + 3];
        float4* sx4 = (float4*)s_x;
#pragma unroll
        for (int i = 0; i < 4; ++i) {
            float4 v = yg[i * 128 + c];
            float4 o;
            o.x = fmaxf(v.x * s0 + h0, 0.f);
            o.y = fmaxf(v.y * s1 + h1, 0.f);
            o.z = fmaxf(v.z * s2 + h2, 0.f);
            o.w = fmaxf(v.w * s3 + h3, 0.f);
            sx4[i * 128 + c] = o;
        }
    }
    __syncthreads();
    float w[64];
    const float4* wr = (const float4*)(w3 + (size_t)c * 64);
#pragma unroll
    for (int t = 0; t < 16; ++t) {
        float4 v = wr[t];
        w[4*t+0] = v.x; w[4*t+1] = v.y; w[4*t+2] = v.z; w[4*t+3] = v.w;
    }
    const float bs = b3[c];
    const float sc = sc3[c], sh = sh3[c];
    float m = -1e30f;
#pragma unroll 2
    for (int k = 0; k < NK; ++k) {
        const float4* xk = (const float4*)(s_x + k * 64);
        float a = bs;
#pragma unroll
        for (int t = 0; t < 16; ++t) {
            float4 v = xk[t];
            a += w[4*t+0] * v.x + w[4*t+1] * v.y + w[4*t+2] * v.z + w[4*t+3] * v.w;
        }
        float r = fmaxf(a * sc + sh, 0.f);
        m = fmaxf(m, r);
    }
    out_np[(size_t)g * 128 + c] = m;
}

// ---------------------------------------------------------------- host launch
extern "C" void kernel_launch(void* const* d_in, const int* in_sizes, int n_in,
                              void* d_out, int out_size, void* d_ws, size_t ws_size,
                              hipStream_t stream)
{
    (void)in_sizes; (void)n_in; (void)out_size;
    const float* xyz = (const float*)d_in[0];
    const float* pts = (const float*)d_in[1];
    const float* w1 = (const float*)d_in[2];
    const float* b1 = (const float*)d_in[3];
    const float* g1 = (const float*)d_in[4];
    const float* be1 = (const float*)d_in[5];
    const float* w2 = (const float*)d_in[6];
    const float* b2 = (const float*)d_in[7];
    const float* g2 = (const float*)d_in[8];
    const float* be2 = (const float*)d_in[9];
    const float* w3 = (const float*)d_in[10];
    const float* b3 = (const float*)d_in[11];
    const float* g3 = (const float*)d_in[12];
    const float* be3 = (const float*)d_in[13];

    float* out = (float*)d_out;
    float* newxyz = out;              // 4*1024*3
    float* newpts = out + NB * NS * 3;

    char* w = (char*)d_ws;
    int* idxb = (int*)w;                               // 131072 ints = 512 KB
    float* y1 = (float*)(w + (512 << 10));             // 8388608 f32
    float* y2 = y1 + 8388608;
    float* st = y2 + 8388608;                          // stats: 3 layers * 2304 f32
    const size_t needed = (512ull << 10) + 2ull * 8388608ull * 4ull + 3ull * 2304ull * 4ull;
    if (ws_size < needed) return;                       // ws too small: bail cleanly

    float* sums1 = st,          *sqs1 = st + 1024,  *sc1 = st + 2048, *sh1 = st + 2176;
    float* st2 = st + 2304;
    float* sums2 = st2,         *sqs2 = st2 + 1024, *sc2 = st2 + 2048, *sh2 = st2 + 2176;
    float* st3 = st + 4608;
    float* sums3 = st3,         *sqs3 = st3 + 1024, *sc3 = st3 + 2048, *sh3 = st3 + 2176;

    hipMemsetAsync(st, 0, 3ull * 2304ull * 4ull, stream);

    fps_kernel<<<NB, 512, 0, stream>>>(xyz, newxyz);
    ballq_kernel<<<1024, 256, 0, stream>>>(xyz, newxyz, idxb);
    linear1_kernel<<<512, 256, 0, stream>>>(xyz, pts, newxyz, idxb, w1, b1, y1);
    stats_kernel<64><<<512, 256, 0, stream>>>(y1, sums1, sqs1);
    finalize_kernel<64><<<1, 64, 0, stream>>>(sums1, sqs1, g1, be1, sc1, sh1);
    linear2_kernel<<<512, 256, 0, stream>>>(y1, sc1, sh1, w2, b2, y2);
    stats_kernel<64><<<512, 256, 0, stream>>>(y2, sums2, sqs2);
    finalize_kernel<64><<<1, 64, 0, stream>>>(sums2, sqs2, g2, be2, sc2, sh2);
    l3stats_kernel<<<4096, 128, 0, stream>>>(y2, sc2, sh2, w3, b3, sums3, sqs3);
    finalize_kernel<128><<<1, 128, 0, stream>>>(sums3, sqs3, g3, be3, sc3, sh3);
    final_kernel<<<4096, 128, 0, stream>>>(y2, sc2, sh2, w3, b3, sc3, sh3, newpts);
}